// Round 5
// baseline (2404.170 us; speedup 1.0000x reference)
//
#include <hip/hip_runtime.h>
#include <stdint.h>

// PillarFeatureNet on MI355X — round 5: coalesced-write restructure.
// B=2, T=5, GX=GY=512, C=64, N=600000. Output (B,C,T,GY,GX) f32 = 671 MB.
//
// r4 passed at 1886 us; k_scatter (scattered 4B atomicMax, 64 lines/wave)
// was 865 us at 10% HBM, plus a ~671MB memset. This round:
//   count -> stats -> finalize -> offsets(dense ids) -> fill(lists, no
//   atomics) -> pillar(wave/pillar max in regs, compact 256B coalesced
//   writes) -> expand(LDS transpose, fully-coalesced 671MB canvas write,
//   replaces the memset).
// Voxelization numerics: (x+51.2f)*5.0f IEEE-pinned f32 (matches oracle's
// canonicalized multiply-by-reciprocal — membership-critical, do not touch).

#define GXc 512
#define GYc 512
#define Bc  2
#define Tc  5
#define Cc  64
#define NSEG (Bc * Tc * GYc * GXc)   // 2,621,440
#define SBc 512                      // stats partial blocks

__device__ __forceinline__ bool point_prep(const float* __restrict__ p,
    float& x, float& y, float& z, float& inten,
    int& bid, int& tid, int& cx, int& cy, int& seg)
{
    float b0 = p[0];
    x = p[1]; y = p[2]; z = p[3]; inten = p[4];
    float tf = p[5];
    float cf0 = __fmul_rn(__fadd_rn(x, 51.2f), 5.0f);
    float cf1 = __fmul_rn(__fadd_rn(y, 51.2f), 5.0f);
    bool valid = (cf0 >= 0.0f) && (cf0 < 512.0f) && (cf1 >= 0.0f) && (cf1 < 512.0f);
    int icx = (int)cf0; icx = icx < 0 ? 0 : (icx > GXc - 1 ? GXc - 1 : icx);
    int icy = (int)cf1; icy = icy < 0 ? 0 : (icy > GYc - 1 ? GYc - 1 : icy);
    cx = icx; cy = icy;
    bid = (int)b0;
    tid = (int)tf;
    seg = ((bid * Tc + tid) * GYc + cy) * GXc + cx;
    return valid;
}

__device__ __forceinline__ float point_x(
    float x, float y, float z, float inten, int cx, int cy, int seg,
    const uint32_t* __restrict__ counts, const float* __restrict__ sums,
    const float* __restrict__ W, int c)
{
    float cnt = (float)counts[seg];
    float m0 = sums[seg * 3 + 0] / cnt;
    float m1 = sums[seg * 3 + 1] / cnt;
    float m2 = sums[seg * 3 + 2] / cnt;
    float ctr0 = __fadd_rn(__fadd_rn(__fmul_rn((float)cx, 0.2f), 0.1f), -51.2f);
    float ctr1 = __fadd_rn(__fadd_rn(__fmul_rn((float)cy, 0.2f), 0.1f), -51.2f);
    float f4 = x - m0, f5 = y - m1, f6 = z - m2;
    float f7 = x - ctr0, f8 = y - ctr1;
    float xc;
    xc = x * W[0 * Cc + c];
    xc = fmaf(y,  W[1 * Cc + c], xc);
    xc = fmaf(z,  W[2 * Cc + c], xc);
    xc = fmaf(inten, W[3 * Cc + c], xc);
    xc = fmaf(f4, W[4 * Cc + c], xc);
    xc = fmaf(f5, W[5 * Cc + c], xc);
    xc = fmaf(f6, W[6 * Cc + c], xc);
    xc = fmaf(f7, W[7 * Cc + c], xc);
    xc = fmaf(f8, W[8 * Cc + c], xc);
    return xc;
}

// ctr[0]=nvalid  ctr[1]=nPillars  ctr[2]=nListed
extern "C" __global__ __launch_bounds__(256)
void k_count(const float* __restrict__ pts, uint32_t* __restrict__ counts,
             float* __restrict__ sums, uint32_t* __restrict__ ctr,
             int* __restrict__ segOf, uint32_t* __restrict__ rankOf, int n)
{
    int i = blockIdx.x * 256 + threadIdx.x;
    if (i >= n) return;
    float x, y, z, it; int bid, tid, cx, cy, seg;
    bool v = point_prep(pts + (size_t)i * 6, x, y, z, it, bid, tid, cx, cy, seg);
    if (segOf) segOf[i] = v ? seg : -1;
    if (!v) return;
    uint32_t r = atomicAdd(&counts[seg], 1u);
    if (rankOf) rankOf[i] = r;
    atomicAdd(&sums[seg * 3 + 0], x);
    atomicAdd(&sums[seg * 3 + 1], y);
    atomicAdd(&sums[seg * 3 + 2], z);
    atomicAdd(&ctr[0], 1u);
}

extern "C" __global__ __launch_bounds__(256)
void k_stats(const float* __restrict__ pts, const uint32_t* __restrict__ counts,
             const float* __restrict__ sums, const float* __restrict__ W,
             double* __restrict__ px, double* __restrict__ px2, int n)
{
    int c = threadIdx.x & 63;
    int sub = threadIdx.x >> 6;
    double ax = 0.0, ax2 = 0.0;
    for (int i = blockIdx.x * 4 + sub; i < n; i += (int)gridDim.x * 4) {
        float x, y, z, it; int bid, tid, cx, cy, seg;
        bool v = point_prep(pts + (size_t)i * 6, x, y, z, it, bid, tid, cx, cy, seg);
        if (!v) continue;
        float xc = point_x(x, y, z, it, cx, cy, seg, counts, sums, W, c);
        ax  += (double)xc;
        ax2 += (double)xc * (double)xc;
    }
    __shared__ double sred[256];
    sred[threadIdx.x] = ax;
    __syncthreads();
    if (sub == 0)
        px[(size_t)blockIdx.x * 64 + c] = sred[c] + sred[c + 64] + sred[c + 128] + sred[c + 192];
    __syncthreads();
    sred[threadIdx.x] = ax2;
    __syncthreads();
    if (sub == 0)
        px2[(size_t)blockIdx.x * 64 + c] = sred[c] + sred[c + 64] + sred[c + 128] + sred[c + 192];
}

extern "C" __global__ __launch_bounds__(256)
void k_finalize(const double* __restrict__ px, const double* __restrict__ px2,
                const uint32_t* __restrict__ ctr,
                const float* __restrict__ gamma, const float* __restrict__ beta,
                float* __restrict__ scale, float* __restrict__ shift)
{
    int c = threadIdx.x & 63;
    int g = threadIdx.x >> 6;
    double sx = 0.0, sx2 = 0.0;
    for (int b = g; b < SBc; b += 4) {
        sx  += px[(size_t)b * 64 + c];
        sx2 += px2[(size_t)b * 64 + c];
    }
    __shared__ double sr[256];
    sr[threadIdx.x] = sx;
    __syncthreads();
    double tsx = 0.0;
    if (g == 0) tsx = sr[c] + sr[c + 64] + sr[c + 128] + sr[c + 192];
    __syncthreads();
    sr[threadIdx.x] = sx2;
    __syncthreads();
    if (g == 0) {
        double tsx2 = sr[c] + sr[c + 64] + sr[c + 128] + sr[c + 192];
        uint32_t nvu = ctr[0]; if (nvu < 1u) nvu = 1u;
        double nv = (double)nvu;
        double mu = tsx / nv;
        double var = tsx2 / nv - mu * mu;
        float r = (float)(1.0 / sqrt(var + 0.001));
        float sc = gamma[c] * r;
        scale[c] = sc;
        shift[c] = fmaf(-(float)mu, sc, beta[c]);
    }
}

extern "C" __global__ __launch_bounds__(256)
void k_offsets(const uint32_t* __restrict__ counts, uint32_t* __restrict__ ctr,
               int* __restrict__ denseOf, uint32_t* __restrict__ offOf,
               int* __restrict__ segOfDense)
{
    int i = blockIdx.x * 256 + threadIdx.x;
    if (i >= NSEG) return;
    uint32_t cnt = counts[i];
    if (cnt > 0) {
        uint32_t d = atomicAdd(&ctr[1], 1u);
        uint32_t o = atomicAdd(&ctr[2], cnt);
        denseOf[i] = (int)d;
        offOf[i] = o;
        segOfDense[d] = i;
    } else {
        denseOf[i] = -1;
    }
}

extern "C" __global__ __launch_bounds__(256)
void k_fill(const int* __restrict__ segOf, const uint32_t* __restrict__ rankOf,
            const uint32_t* __restrict__ offOf, uint32_t* __restrict__ list, int n)
{
    int i = blockIdx.x * 256 + threadIdx.x;
    if (i >= n) return;
    int s = segOf[i];
    if (s < 0) return;
    list[offOf[s] + rankOf[i]] = (uint32_t)i;
}

// One wave per occupied pillar; lane = channel. Max over its points in
// registers (no atomics); compact row write is a coalesced 256B store.
extern "C" __global__ __launch_bounds__(256)
void k_pillar(const float* __restrict__ pts, const uint32_t* __restrict__ counts,
              const float* __restrict__ sums, const uint32_t* __restrict__ offOf,
              const int* __restrict__ segOfDense, const uint32_t* __restrict__ list,
              const float* __restrict__ W, const float* __restrict__ scale,
              const float* __restrict__ shift, const uint32_t* __restrict__ ctr,
              float* __restrict__ compact)
{
    int lane = threadIdx.x & 63;
    uint32_t d = blockIdx.x * 4 + (threadIdx.x >> 6);
    if (d >= ctr[1]) return;
    int seg = segOfDense[d];
    uint32_t cnt = counts[seg];
    uint32_t off = offOf[seg];
    float fc = (float)cnt;
    float m0 = sums[seg * 3 + 0] / fc;
    float m1 = sums[seg * 3 + 1] / fc;
    float m2 = sums[seg * 3 + 2] / fc;
    int cx = seg & (GXc - 1);
    int cy = (seg >> 9) & (GYc - 1);
    float ctr0 = __fadd_rn(__fadd_rn(__fmul_rn((float)cx, 0.2f), 0.1f), -51.2f);
    float ctr1 = __fadd_rn(__fadd_rn(__fmul_rn((float)cy, 0.2f), 0.1f), -51.2f);
    float w0 = W[0 * Cc + lane], w1 = W[1 * Cc + lane], w2 = W[2 * Cc + lane];
    float w3 = W[3 * Cc + lane], w4 = W[4 * Cc + lane], w5 = W[5 * Cc + lane];
    float w6 = W[6 * Cc + lane], w7 = W[7 * Cc + lane], w8 = W[8 * Cc + lane];
    float sc = scale[lane], sh = shift[lane];
    float acc = 0.0f;   // relu identity
    for (uint32_t p = 0; p < cnt; p++) {
        const float* P = pts + (size_t)list[off + p] * 6;
        float x = P[1], y = P[2], z = P[3], it = P[4];
        float xc;
        xc = x * w0;
        xc = fmaf(y,  w1, xc);
        xc = fmaf(z,  w2, xc);
        xc = fmaf(it, w3, xc);
        xc = fmaf(x - m0, w4, xc);
        xc = fmaf(y - m1, w5, xc);
        xc = fmaf(z - m2, w6, xc);
        xc = fmaf(x - ctr0, w7, xc);
        xc = fmaf(y - ctr1, w8, xc);
        float yv = fmaf(xc, sc, sh);
        acc = fmaxf(acc, yv);
    }
    compact[(size_t)d * 64 + lane] = acc;
}

// Expand compact -> full canvas, fully coalesced; writes every cell (so no
// canvas memset needed). Block handles 128 consecutive segs x 64 channels
// through an LDS transpose tile padded to 65 (conflict-free both phases).
extern "C" __global__ __launch_bounds__(256)
void k_expand(const float* __restrict__ compact, const int* __restrict__ denseOf,
              float* __restrict__ out)
{
    __shared__ int sdense[128];
    __shared__ float tile[128 * 65];
    int tid = threadIdx.x;
    int s0 = blockIdx.x * 128;
    if (tid < 128) sdense[tid] = denseOf[s0 + tid];
    __syncthreads();
    int w = tid >> 6, lane = tid & 63;
    for (int k = 0; k < 32; k++) {
        int p = w * 32 + k;
        int d = sdense[p];
        float v = 0.0f;
        if (d >= 0) v = compact[(size_t)d * 64 + lane];
        tile[p * 65 + lane] = v;
    }
    __syncthreads();
    int gx0 = s0 & (GXc - 1);
    int gy  = (s0 >> 9) & (GYc - 1);
    int bt  = s0 >> 18;            // b*T + t
    int t   = bt % Tc;
    int b   = bt / Tc;
    int p   = tid & 127;
    int ch  = tid >> 7;            // 0 or 1
    size_t rowbase = ((size_t)gy << 9) + gx0 + p;
    for (int cc = 0; cc < 64; cc += 2) {
        int c = cc + ch;
        size_t o = ((((size_t)b * Cc + c) * Tc + t) << 18) + rowbase;
        out[o] = tile[p * 65 + c];
    }
}

// Fallback scatter (r4 path) if ws is too small for the compact pipeline.
extern "C" __global__ __launch_bounds__(256)
void k_scatter(const float* __restrict__ pts, const uint32_t* __restrict__ counts,
               const float* __restrict__ sums, const float* __restrict__ W,
               const float* __restrict__ scale, const float* __restrict__ shift,
               unsigned int* __restrict__ out, int n)
{
    int c = threadIdx.x & 63;
    int sub = threadIdx.x >> 6;
    int i = blockIdx.x * 4 + sub;
    if (i >= n) return;
    float x, y, z, it; int bid, tid, cx, cy, seg;
    bool v = point_prep(pts + (size_t)i * 6, x, y, z, it, bid, tid, cx, cy, seg);
    if (!v) return;
    float xc = point_x(x, y, z, it, cx, cy, seg, counts, sums, W, c);
    float yv = fmaf(xc, scale[c], shift[c]);
    if (yv > 0.0f) {
        size_t oidx = ((((size_t)bid * Cc + c) * Tc + tid) * ((size_t)GYc * GXc))
                    + (size_t)cy * GXc + cx;
        atomicMax(&out[oidx], __float_as_uint(yv));
    }
}

extern "C" void kernel_launch(void* const* d_in, const int* in_sizes, int n_in,
                              void* d_out, int out_size, void* d_ws, size_t ws_size,
                              hipStream_t stream)
{
    const float* pts   = (const float*)d_in[0];
    const float* W     = (const float*)d_in[1];
    const float* gamma = (const float*)d_in[2];
    const float* beta  = (const float*)d_in[3];
    int n = in_sizes[0] / 6;

    uint8_t* ws = (uint8_t*)d_ws;
    const size_t OFF_CTR    = 0;                                  // 256 B
    const size_t OFF_COUNTS = 256;
    const size_t OFF_SUMS   = OFF_COUNTS + (size_t)NSEG * 4;
    const size_t ZERO_END   = OFF_SUMS + (size_t)NSEG * 3 * 4;    // 41,943,296
    const size_t OFF_PX     = ZERO_END;
    const size_t OFF_PX2    = OFF_PX  + (size_t)SBc * 64 * 8;
    const size_t OFF_SCALE  = OFF_PX2 + (size_t)SBc * 64 * 8;
    const size_t OFF_SHIFT  = OFF_SCALE + 256;
    const size_t OFF_DENSE  = OFF_SHIFT + 256;
    const size_t OFF_OFFOF  = OFF_DENSE + (size_t)NSEG * 4;
    size_t npad = ((size_t)n * 4 + 255) & ~(size_t)255;
    const size_t OFF_SEGOF  = OFF_OFFOF + (size_t)NSEG * 4;
    const size_t OFF_RANK   = OFF_SEGOF + npad;
    const size_t OFF_SDENSE = OFF_RANK + npad;   // segOfDense
    const size_t OFF_LIST   = OFF_SDENSE + npad;
    const size_t OFF_COMP   = OFF_LIST + npad;
    const size_t needed     = OFF_COMP + (size_t)n * 64 * 4;

    uint32_t* ctr     = (uint32_t*)(ws + OFF_CTR);
    uint32_t* counts  = (uint32_t*)(ws + OFF_COUNTS);
    float*    sums    = (float*)(ws + OFF_SUMS);
    double*   px      = (double*)(ws + OFF_PX);
    double*   px2     = (double*)(ws + OFF_PX2);
    float*    scale   = (float*)(ws + OFF_SCALE);
    float*    shift   = (float*)(ws + OFF_SHIFT);
    int*      denseOf = (int*)(ws + OFF_DENSE);
    uint32_t* offOf   = (uint32_t*)(ws + OFF_OFFOF);
    int*      segOf   = (int*)(ws + OFF_SEGOF);
    uint32_t* rankOf  = (uint32_t*)(ws + OFF_RANK);
    int*      segOfD  = (int*)(ws + OFF_SDENSE);
    uint32_t* list    = (uint32_t*)(ws + OFF_LIST);
    float*    compact = (float*)(ws + OFF_COMP);

    bool fast = (ws_size >= needed);

    hipMemsetAsync(ws, 0, ZERO_END, stream);   // ctr + counts + sums

    if (fast) {
        k_count   <<<(n + 255) / 256, 256, 0, stream>>>(pts, counts, sums, ctr,
                                                        segOf, rankOf, n);
        k_stats   <<<SBc, 256, 0, stream>>>(pts, counts, sums, W, px, px2, n);
        k_finalize<<<1, 256, 0, stream>>>(px, px2, ctr, gamma, beta, scale, shift);
        k_offsets <<<(NSEG + 255) / 256, 256, 0, stream>>>(counts, ctr, denseOf,
                                                           offOf, segOfD);
        k_fill    <<<(n + 255) / 256, 256, 0, stream>>>(segOf, rankOf, offOf, list, n);
        k_pillar  <<<(n + 3) / 4, 256, 0, stream>>>(pts, counts, sums, offOf, segOfD,
                                                    list, W, scale, shift, ctr, compact);
        k_expand  <<<NSEG / 128, 256, 0, stream>>>(compact, denseOf, (float*)d_out);
    } else {
        hipMemsetAsync(d_out, 0, (size_t)out_size * sizeof(float), stream);
        k_count   <<<(n + 255) / 256, 256, 0, stream>>>(pts, counts, sums, ctr,
                                                        (int*)nullptr, (uint32_t*)nullptr, n);
        k_stats   <<<SBc, 256, 0, stream>>>(pts, counts, sums, W, px, px2, n);
        k_finalize<<<1, 256, 0, stream>>>(px, px2, ctr, gamma, beta, scale, shift);
        k_scatter <<<(n + 3) / 4, 256, 0, stream>>>(pts, counts, sums, W, scale, shift,
                                                    (unsigned int*)d_out, n);
    }
}

// Round 6
// 1405.576 us; speedup vs baseline: 1.7105x; 1.7105x over previous
//
#include <hip/hip_runtime.h>
#include <stdint.h>

// PillarFeatureNet on MI355X — round 6.
// r5 regressed: k_offsets spent 930 us on ~950k same-address global atomics
// (two counters). Replaced with block-scan + ONE packed u64 atomic per
// 1024-thread block (2560 atomics total). k_stats grid 512->2048.
//
// Pipeline: count -> stats -> finalize -> offsets(scan) -> fill -> pillar
// (wave/pillar, max in regs, compact coalesced) -> expand (LDS transpose,
// fully-coalesced 671MB canvas write, replaces canvas memset).
// Voxelization numerics: (x+51.2f)*5.0f IEEE-pinned f32 — membership-
// critical, matches the oracle's multiply-by-reciprocal. DO NOT TOUCH.

#define GXc 512
#define GYc 512
#define Bc  2
#define Tc  5
#define Cc  64
#define NSEG (Bc * Tc * GYc * GXc)   // 2,621,440
#define SBc 2048                     // stats partial blocks

__device__ __forceinline__ bool point_prep(const float* __restrict__ p,
    float& x, float& y, float& z, float& inten,
    int& bid, int& tid, int& cx, int& cy, int& seg)
{
    float b0 = p[0];
    x = p[1]; y = p[2]; z = p[3]; inten = p[4];
    float tf = p[5];
    float cf0 = __fmul_rn(__fadd_rn(x, 51.2f), 5.0f);
    float cf1 = __fmul_rn(__fadd_rn(y, 51.2f), 5.0f);
    bool valid = (cf0 >= 0.0f) && (cf0 < 512.0f) && (cf1 >= 0.0f) && (cf1 < 512.0f);
    int icx = (int)cf0; icx = icx < 0 ? 0 : (icx > GXc - 1 ? GXc - 1 : icx);
    int icy = (int)cf1; icy = icy < 0 ? 0 : (icy > GYc - 1 ? GYc - 1 : icy);
    cx = icx; cy = icy;
    bid = (int)b0;
    tid = (int)tf;
    seg = ((bid * Tc + tid) * GYc + cy) * GXc + cx;
    return valid;
}

__device__ __forceinline__ float point_x(
    float x, float y, float z, float inten, int cx, int cy, int seg,
    const uint32_t* __restrict__ counts, const float* __restrict__ sums,
    const float* __restrict__ W, int c)
{
    float cnt = (float)counts[seg];
    float m0 = sums[seg * 3 + 0] / cnt;
    float m1 = sums[seg * 3 + 1] / cnt;
    float m2 = sums[seg * 3 + 2] / cnt;
    float ctr0 = __fadd_rn(__fadd_rn(__fmul_rn((float)cx, 0.2f), 0.1f), -51.2f);
    float ctr1 = __fadd_rn(__fadd_rn(__fmul_rn((float)cy, 0.2f), 0.1f), -51.2f);
    float f4 = x - m0, f5 = y - m1, f6 = z - m2;
    float f7 = x - ctr0, f8 = y - ctr1;
    float xc;
    xc = x * W[0 * Cc + c];
    xc = fmaf(y,  W[1 * Cc + c], xc);
    xc = fmaf(z,  W[2 * Cc + c], xc);
    xc = fmaf(inten, W[3 * Cc + c], xc);
    xc = fmaf(f4, W[4 * Cc + c], xc);
    xc = fmaf(f5, W[5 * Cc + c], xc);
    xc = fmaf(f6, W[6 * Cc + c], xc);
    xc = fmaf(f7, W[7 * Cc + c], xc);
    xc = fmaf(f8, W[8 * Cc + c], xc);
    return xc;
}

// ctr[0]=nvalid ; ctr[2..3] = packed u64 counter (low32=points, high32=pillars)
extern "C" __global__ __launch_bounds__(256)
void k_count(const float* __restrict__ pts, uint32_t* __restrict__ counts,
             float* __restrict__ sums, uint32_t* __restrict__ ctr,
             int* __restrict__ segOf, uint32_t* __restrict__ rankOf, int n)
{
    int i = blockIdx.x * 256 + threadIdx.x;
    if (i >= n) return;
    float x, y, z, it; int bid, tid, cx, cy, seg;
    bool v = point_prep(pts + (size_t)i * 6, x, y, z, it, bid, tid, cx, cy, seg);
    segOf[i] = v ? seg : -1;
    if (!v) return;
    uint32_t r = atomicAdd(&counts[seg], 1u);
    rankOf[i] = r;
    atomicAdd(&sums[seg * 3 + 0], x);
    atomicAdd(&sums[seg * 3 + 1], y);
    atomicAdd(&sums[seg * 3 + 2], z);
    atomicAdd(&ctr[0], 1u);   // compiler coalesces per-wave
}

extern "C" __global__ __launch_bounds__(256)
void k_stats(const float* __restrict__ pts, const uint32_t* __restrict__ counts,
             const float* __restrict__ sums, const float* __restrict__ W,
             double* __restrict__ px, double* __restrict__ px2, int n)
{
    int c = threadIdx.x & 63;
    int sub = threadIdx.x >> 6;
    double ax = 0.0, ax2 = 0.0;
    for (int i = blockIdx.x * 4 + sub; i < n; i += (int)gridDim.x * 4) {
        float x, y, z, it; int bid, tid, cx, cy, seg;
        bool v = point_prep(pts + (size_t)i * 6, x, y, z, it, bid, tid, cx, cy, seg);
        if (!v) continue;
        float xc = point_x(x, y, z, it, cx, cy, seg, counts, sums, W, c);
        ax  += (double)xc;
        ax2 += (double)xc * (double)xc;
    }
    __shared__ double sred[256];
    sred[threadIdx.x] = ax;
    __syncthreads();
    if (sub == 0)
        px[(size_t)blockIdx.x * 64 + c] = sred[c] + sred[c + 64] + sred[c + 128] + sred[c + 192];
    __syncthreads();
    sred[threadIdx.x] = ax2;
    __syncthreads();
    if (sub == 0)
        px2[(size_t)blockIdx.x * 64 + c] = sred[c] + sred[c + 64] + sred[c + 128] + sred[c + 192];
}

extern "C" __global__ __launch_bounds__(256)
void k_finalize(const double* __restrict__ px, const double* __restrict__ px2,
                const uint32_t* __restrict__ ctr,
                const float* __restrict__ gamma, const float* __restrict__ beta,
                float* __restrict__ scale, float* __restrict__ shift)
{
    int c = threadIdx.x & 63;
    int g = threadIdx.x >> 6;
    double sx = 0.0, sx2 = 0.0;
    for (int b = g; b < SBc; b += 4) {
        sx  += px[(size_t)b * 64 + c];
        sx2 += px2[(size_t)b * 64 + c];
    }
    __shared__ double sr[256];
    sr[threadIdx.x] = sx;
    __syncthreads();
    double tsx = 0.0;
    if (g == 0) tsx = sr[c] + sr[c + 64] + sr[c + 128] + sr[c + 192];
    __syncthreads();
    sr[threadIdx.x] = sx2;
    __syncthreads();
    if (g == 0) {
        double tsx2 = sr[c] + sr[c + 64] + sr[c + 128] + sr[c + 192];
        uint32_t nvu = ctr[0]; if (nvu < 1u) nvu = 1u;
        double nv = (double)nvu;
        double mu = tsx / nv;
        double var = tsx2 / nv - mu * mu;
        float r = (float)(1.0 / sqrt(var + 0.001));
        float sc = gamma[c] * r;
        scale[c] = sc;
        shift[c] = fmaf(-(float)mu, sc, beta[c]);
    }
}

// Dense-id + offset assignment via block scan; ONE u64 atomic per block.
// Packed: high32 = occupied-pillar count, low32 = point count. Fields can't
// overlap (block totals <= 1024 and <= sum(counts) < 2^32).
extern "C" __global__ __launch_bounds__(1024)
void k_offsets(const uint32_t* __restrict__ counts, uint32_t* __restrict__ ctr,
               int* __restrict__ denseOf, uint32_t* __restrict__ offOf,
               int* __restrict__ segOfDense)
{
    int tid = threadIdx.x;
    int i = blockIdx.x * 1024 + tid;
    uint32_t cnt = (i < NSEG) ? counts[i] : 0u;
    uint32_t occ = (cnt > 0u) ? 1u : 0u;
    unsigned long long v = ((unsigned long long)occ << 32) | (unsigned long long)cnt;
    unsigned long long inc = v;
    int lane = tid & 63, wid = tid >> 6;
    #pragma unroll
    for (int d = 1; d < 64; d <<= 1) {
        unsigned long long t = __shfl_up(inc, d, 64);
        if (lane >= d) inc += t;
    }
    __shared__ unsigned long long wtot[16];
    __shared__ unsigned long long wbase[16];
    __shared__ unsigned long long gbase;
    if (lane == 63) wtot[wid] = inc;
    __syncthreads();
    if (wid == 0) {
        unsigned long long w = (lane < 16) ? wtot[lane] : 0ull;
        unsigned long long s = w;
        #pragma unroll
        for (int d = 1; d < 16; d <<= 1) {
            unsigned long long t = __shfl_up(s, d, 64);
            if (lane >= d) s += t;
        }
        if (lane < 16) wbase[lane] = s - w;          // exclusive wave base
        if (lane == 15)
            gbase = atomicAdd((unsigned long long*)(ctr + 2), s);  // block total
    }
    __syncthreads();
    if (i >= NSEG) return;
    unsigned long long ex = gbase + wbase[wid] + (inc - v);  // exclusive global
    if (occ) {
        uint32_t d = (uint32_t)(ex >> 32);
        uint32_t o = (uint32_t)ex;
        denseOf[i] = (int)d;
        offOf[i] = o;
        segOfDense[d] = i;
    } else {
        denseOf[i] = -1;
    }
}

extern "C" __global__ __launch_bounds__(256)
void k_fill(const int* __restrict__ segOf, const uint32_t* __restrict__ rankOf,
            const uint32_t* __restrict__ offOf, uint32_t* __restrict__ list, int n)
{
    int i = blockIdx.x * 256 + threadIdx.x;
    if (i >= n) return;
    int s = segOf[i];
    if (s < 0) return;
    list[offOf[s] + rankOf[i]] = (uint32_t)i;
}

// One wave per occupied pillar; lane = channel. Max in registers, coalesced
// 256B compact-row store. nPillars = high word of the packed counter.
extern "C" __global__ __launch_bounds__(256)
void k_pillar(const float* __restrict__ pts, const uint32_t* __restrict__ counts,
              const float* __restrict__ sums, const uint32_t* __restrict__ offOf,
              const int* __restrict__ segOfDense, const uint32_t* __restrict__ list,
              const float* __restrict__ W, const float* __restrict__ scale,
              const float* __restrict__ shift, const uint32_t* __restrict__ ctr,
              float* __restrict__ compact)
{
    int lane = threadIdx.x & 63;
    uint32_t d = blockIdx.x * 4 + (threadIdx.x >> 6);
    if (d >= ctr[3]) return;                 // high32 of packed counter
    int seg = segOfDense[d];
    uint32_t cnt = counts[seg];
    uint32_t off = offOf[seg];
    float fc = (float)cnt;
    float m0 = sums[seg * 3 + 0] / fc;
    float m1 = sums[seg * 3 + 1] / fc;
    float m2 = sums[seg * 3 + 2] / fc;
    int cx = seg & (GXc - 1);
    int cy = (seg >> 9) & (GYc - 1);
    float ctr0 = __fadd_rn(__fadd_rn(__fmul_rn((float)cx, 0.2f), 0.1f), -51.2f);
    float ctr1 = __fadd_rn(__fadd_rn(__fmul_rn((float)cy, 0.2f), 0.1f), -51.2f);
    float w0 = W[0 * Cc + lane], w1 = W[1 * Cc + lane], w2 = W[2 * Cc + lane];
    float w3 = W[3 * Cc + lane], w4 = W[4 * Cc + lane], w5 = W[5 * Cc + lane];
    float w6 = W[6 * Cc + lane], w7 = W[7 * Cc + lane], w8 = W[8 * Cc + lane];
    float sc = scale[lane], sh = shift[lane];
    float acc = 0.0f;   // relu identity
    for (uint32_t p = 0; p < cnt; p++) {
        const float* P = pts + (size_t)list[off + p] * 6;
        float x = P[1], y = P[2], z = P[3], it = P[4];
        float xc;
        xc = x * w0;
        xc = fmaf(y,  w1, xc);
        xc = fmaf(z,  w2, xc);
        xc = fmaf(it, w3, xc);
        xc = fmaf(x - m0, w4, xc);
        xc = fmaf(y - m1, w5, xc);
        xc = fmaf(z - m2, w6, xc);
        xc = fmaf(x - ctr0, w7, xc);
        xc = fmaf(y - ctr1, w8, xc);
        float yv = fmaf(xc, sc, sh);
        acc = fmaxf(acc, yv);
    }
    compact[(size_t)d * 64 + lane] = acc;
}

// Expand compact -> full canvas, fully coalesced; writes every cell (so no
// canvas memset). 128 consecutive segs x 64 ch via LDS tile padded to 65.
extern "C" __global__ __launch_bounds__(256)
void k_expand(const float* __restrict__ compact, const int* __restrict__ denseOf,
              float* __restrict__ out)
{
    __shared__ int sdense[128];
    __shared__ float tile[128 * 65];
    int tid = threadIdx.x;
    int s0 = blockIdx.x * 128;
    if (tid < 128) sdense[tid] = denseOf[s0 + tid];
    __syncthreads();
    int w = tid >> 6, lane = tid & 63;
    for (int k = 0; k < 32; k++) {
        int p = w * 32 + k;
        int d = sdense[p];
        float v = 0.0f;
        if (d >= 0) v = compact[(size_t)d * 64 + lane];
        tile[p * 65 + lane] = v;
    }
    __syncthreads();
    int gx0 = s0 & (GXc - 1);
    int gy  = (s0 >> 9) & (GYc - 1);
    int bt  = s0 >> 18;            // b*T + t
    int t   = bt % Tc;
    int b   = bt / Tc;
    int p   = tid & 127;
    int ch  = tid >> 7;            // 0 or 1
    size_t rowbase = ((size_t)gy << 9) + gx0 + p;
    for (int cc = 0; cc < 64; cc += 2) {
        int c = cc + ch;
        size_t o = ((((size_t)b * Cc + c) * Tc + t) << 18) + rowbase;
        out[o] = tile[p * 65 + c];
    }
}

extern "C" void kernel_launch(void* const* d_in, const int* in_sizes, int n_in,
                              void* d_out, int out_size, void* d_ws, size_t ws_size,
                              hipStream_t stream)
{
    const float* pts   = (const float*)d_in[0];
    const float* W     = (const float*)d_in[1];
    const float* gamma = (const float*)d_in[2];
    const float* beta  = (const float*)d_in[3];
    int n = in_sizes[0] / 6;

    uint8_t* ws = (uint8_t*)d_ws;
    const size_t OFF_CTR    = 0;                                  // 256 B
    const size_t OFF_COUNTS = 256;
    const size_t OFF_SUMS   = OFF_COUNTS + (size_t)NSEG * 4;
    const size_t ZERO_END   = OFF_SUMS + (size_t)NSEG * 3 * 4;
    const size_t OFF_PX     = ZERO_END;
    const size_t OFF_PX2    = OFF_PX  + (size_t)SBc * 64 * 8;
    const size_t OFF_SCALE  = OFF_PX2 + (size_t)SBc * 64 * 8;
    const size_t OFF_SHIFT  = OFF_SCALE + 256;
    const size_t OFF_DENSE  = OFF_SHIFT + 256;
    const size_t OFF_OFFOF  = OFF_DENSE + (size_t)NSEG * 4;
    size_t npad = ((size_t)n * 4 + 255) & ~(size_t)255;
    const size_t OFF_SEGOF  = OFF_OFFOF + (size_t)NSEG * 4;
    const size_t OFF_RANK   = OFF_SEGOF + npad;
    const size_t OFF_SDENSE = OFF_RANK + npad;
    const size_t OFF_LIST   = OFF_SDENSE + npad;
    const size_t OFF_COMP   = OFF_LIST + npad;

    uint32_t* ctr     = (uint32_t*)(ws + OFF_CTR);
    uint32_t* counts  = (uint32_t*)(ws + OFF_COUNTS);
    float*    sums    = (float*)(ws + OFF_SUMS);
    double*   px      = (double*)(ws + OFF_PX);
    double*   px2     = (double*)(ws + OFF_PX2);
    float*    scale   = (float*)(ws + OFF_SCALE);
    float*    shift   = (float*)(ws + OFF_SHIFT);
    int*      denseOf = (int*)(ws + OFF_DENSE);
    uint32_t* offOf   = (uint32_t*)(ws + OFF_OFFOF);
    int*      segOf   = (int*)(ws + OFF_SEGOF);
    uint32_t* rankOf  = (uint32_t*)(ws + OFF_RANK);
    int*      segOfD  = (int*)(ws + OFF_SDENSE);
    uint32_t* list    = (uint32_t*)(ws + OFF_LIST);
    float*    compact = (float*)(ws + OFF_COMP);

    hipMemsetAsync(ws, 0, ZERO_END, stream);   // ctr + counts + sums

    k_count   <<<(n + 255) / 256, 256, 0, stream>>>(pts, counts, sums, ctr,
                                                    segOf, rankOf, n);
    k_stats   <<<SBc, 256, 0, stream>>>(pts, counts, sums, W, px, px2, n);
    k_finalize<<<1, 256, 0, stream>>>(px, px2, ctr, gamma, beta, scale, shift);
    k_offsets <<<(NSEG + 1023) / 1024, 1024, 0, stream>>>(counts, ctr, denseOf,
                                                          offOf, segOfD);
    k_fill    <<<(n + 255) / 256, 256, 0, stream>>>(segOf, rankOf, offOf, list, n);
    k_pillar  <<<(n + 3) / 4, 256, 0, stream>>>(pts, counts, sums, offOf, segOfD,
                                                list, W, scale, shift, ctr, compact);
    k_expand  <<<NSEG / 128, 256, 0, stream>>>(compact, denseOf, (float*)d_out);
}

// Round 7
// 1189.908 us; speedup vs baseline: 2.0205x; 1.1812x over previous
//
#include <hip/hip_runtime.h>
#include <stdint.h>
#include <float.h>

// PillarFeatureNet on MI355X — round 7: fuse stats into pillar, de-atomize.
// B=2, T=5, GX=GY=512, C=64, N=600000. Output (B,C,T,GY,GX) f32 = 671 MB.
//
// r6 = 1405 us. Profile top-5 = harness 0xAA ws-poison fills (430 us each,
// not ours). Remaining time: k_count (4 scattered atomics/pt), k_stats (an
// entire extra pass), k_fill, k_pillar, k_expand (671 MB, ~the floor).
//
// This round:
//  - k_stats DELETED: k_pillar accumulates f64 sum(x),sum(x^2) while it
//    computes xc; stores per-pillar (max,min) PRE-BN. k_expand applies
//    relu(s*sel+t) with sel = (s>=0 ? max : min)  — exact by monotonicity.
//  - k_count: only counts[seg] atomic (+rank); pillar xyz-means computed
//    locally in k_pillar from the list (sequential f32).
//  - k_pillar: grid-stride 2048 blocks, block-level f64 stat partials.
// Voxelization numerics: (x+51.2f)*5.0f IEEE-pinned f32 — membership-
// critical, matches the oracle's multiply-by-reciprocal. DO NOT TOUCH.

#define GXc 512
#define GYc 512
#define Bc  2
#define Tc  5
#define Cc  64
#define NSEG (Bc * Tc * GYc * GXc)   // 2,621,440
#define SBc 2048                     // stat partial rows (= k_pillar grid)

__device__ __forceinline__ bool point_prep(const float* __restrict__ p,
    float& x, float& y, float& z, float& inten,
    int& bid, int& tid, int& cx, int& cy, int& seg)
{
    float b0 = p[0];
    x = p[1]; y = p[2]; z = p[3]; inten = p[4];
    float tf = p[5];
    float cf0 = __fmul_rn(__fadd_rn(x, 51.2f), 5.0f);
    float cf1 = __fmul_rn(__fadd_rn(y, 51.2f), 5.0f);
    bool valid = (cf0 >= 0.0f) && (cf0 < 512.0f) && (cf1 >= 0.0f) && (cf1 < 512.0f);
    int icx = (int)cf0; icx = icx < 0 ? 0 : (icx > GXc - 1 ? GXc - 1 : icx);
    int icy = (int)cf1; icy = icy < 0 ? 0 : (icy > GYc - 1 ? GYc - 1 : icy);
    cx = icx; cy = icy;
    bid = (int)b0;
    tid = (int)tf;
    seg = ((bid * Tc + tid) * GYc + cy) * GXc + cx;
    return valid;
}

// ctr[2..3] = packed u64 scan counter (low32 = points = nvalid, high32 = pillars)
extern "C" __global__ __launch_bounds__(256)
void k_count(const float* __restrict__ pts, uint32_t* __restrict__ counts,
             uint32_t* __restrict__ ctr,
             int* __restrict__ segOf, uint32_t* __restrict__ rankOf, int n)
{
    int i = blockIdx.x * 256 + threadIdx.x;
    if (i >= n) return;
    float x, y, z, it; int bid, tid, cx, cy, seg;
    bool v = point_prep(pts + (size_t)i * 6, x, y, z, it, bid, tid, cx, cy, seg);
    segOf[i] = v ? seg : -1;
    if (!v) return;
    rankOf[i] = atomicAdd(&counts[seg], 1u);
}

// Dense-id + offset assignment via block scan; ONE u64 atomic per block.
extern "C" __global__ __launch_bounds__(1024)
void k_offsets(const uint32_t* __restrict__ counts, uint32_t* __restrict__ ctr,
               int* __restrict__ denseOf, uint32_t* __restrict__ offOf,
               int* __restrict__ segOfDense)
{
    int tid = threadIdx.x;
    int i = blockIdx.x * 1024 + tid;
    uint32_t cnt = (i < NSEG) ? counts[i] : 0u;
    uint32_t occ = (cnt > 0u) ? 1u : 0u;
    unsigned long long v = ((unsigned long long)occ << 32) | (unsigned long long)cnt;
    unsigned long long inc = v;
    int lane = tid & 63, wid = tid >> 6;
    #pragma unroll
    for (int d = 1; d < 64; d <<= 1) {
        unsigned long long t = __shfl_up(inc, d, 64);
        if (lane >= d) inc += t;
    }
    __shared__ unsigned long long wtot[16];
    __shared__ unsigned long long wbase[16];
    __shared__ unsigned long long gbase;
    if (lane == 63) wtot[wid] = inc;
    __syncthreads();
    if (wid == 0) {
        unsigned long long w = (lane < 16) ? wtot[lane] : 0ull;
        unsigned long long s = w;
        #pragma unroll
        for (int d = 1; d < 16; d <<= 1) {
            unsigned long long t = __shfl_up(s, d, 64);
            if (lane >= d) s += t;
        }
        if (lane < 16) wbase[lane] = s - w;
        if (lane == 15)
            gbase = atomicAdd((unsigned long long*)(ctr + 2), s);
    }
    __syncthreads();
    if (i >= NSEG) return;
    unsigned long long ex = gbase + wbase[wid] + (inc - v);
    if (occ) {
        uint32_t d = (uint32_t)(ex >> 32);
        uint32_t o = (uint32_t)ex;
        denseOf[i] = (int)d;
        offOf[i] = o;
        segOfDense[d] = i;
    } else {
        denseOf[i] = -1;
    }
}

extern "C" __global__ __launch_bounds__(256)
void k_fill(const int* __restrict__ segOf, const uint32_t* __restrict__ rankOf,
            const uint32_t* __restrict__ offOf, uint32_t* __restrict__ list, int n)
{
    int i = blockIdx.x * 256 + threadIdx.x;
    if (i >= n) return;
    int s = segOf[i];
    if (s < 0) return;
    list[offOf[s] + rankOf[i]] = (uint32_t)i;
}

// Grid-stride over occupied pillars; one wave per pillar, lane = channel.
// Pass 1: local xyz-mean from the list. Pass 2: xc per point; f64 stats
// accumulate; per-pillar (max,min) of PRE-BN xc stored as float2.
// Block writes one 64-ch f64 partial row for sum and sum^2.
extern "C" __global__ __launch_bounds__(256)
void k_pillar(const float* __restrict__ pts, const uint32_t* __restrict__ counts,
              const uint32_t* __restrict__ offOf, const int* __restrict__ segOfDense,
              const uint32_t* __restrict__ list, const float* __restrict__ W,
              const uint32_t* __restrict__ ctr,
              float2* __restrict__ compact,
              double* __restrict__ px, double* __restrict__ px2)
{
    int lane = threadIdx.x & 63;
    int sub  = threadIdx.x >> 6;
    uint32_t nP = ctr[3];                       // high32 of packed counter
    float w0 = W[0 * Cc + lane], w1 = W[1 * Cc + lane], w2 = W[2 * Cc + lane];
    float w3 = W[3 * Cc + lane], w4 = W[4 * Cc + lane], w5 = W[5 * Cc + lane];
    float w6 = W[6 * Cc + lane], w7 = W[7 * Cc + lane], w8 = W[8 * Cc + lane];
    double ax = 0.0, ax2 = 0.0;
    for (uint32_t d = blockIdx.x * 4 + sub; d < nP; d += (uint32_t)gridDim.x * 4) {
        int seg = segOfDense[d];
        uint32_t cnt = counts[seg];
        uint32_t off = offOf[seg];
        // pass 1: pillar mean (lanes redundant; broadcast loads)
        float sx = 0.f, sy = 0.f, sz = 0.f;
        for (uint32_t p = 0; p < cnt; p++) {
            const float* P = pts + (size_t)list[off + p] * 6;
            sx += P[1]; sy += P[2]; sz += P[3];
        }
        float fc = (float)cnt;
        float m0 = sx / fc, m1 = sy / fc, m2 = sz / fc;
        int cx = seg & (GXc - 1);
        int cy = (seg >> 9) & (GYc - 1);
        float ctr0 = __fadd_rn(__fadd_rn(__fmul_rn((float)cx, 0.2f), 0.1f), -51.2f);
        float ctr1 = __fadd_rn(__fadd_rn(__fmul_rn((float)cy, 0.2f), 0.1f), -51.2f);
        float mx = -FLT_MAX, mn = FLT_MAX;
        for (uint32_t p = 0; p < cnt; p++) {
            const float* P = pts + (size_t)list[off + p] * 6;
            float x = P[1], y = P[2], z = P[3], it = P[4];
            float xc;
            xc = x * w0;
            xc = fmaf(y,  w1, xc);
            xc = fmaf(z,  w2, xc);
            xc = fmaf(it, w3, xc);
            xc = fmaf(x - m0, w4, xc);
            xc = fmaf(y - m1, w5, xc);
            xc = fmaf(z - m2, w6, xc);
            xc = fmaf(x - ctr0, w7, xc);
            xc = fmaf(y - ctr1, w8, xc);
            ax  += (double)xc;
            ax2 = fma((double)xc, (double)xc, ax2);
            mx = fmaxf(mx, xc);
            mn = fminf(mn, xc);
        }
        compact[(size_t)d * 64 + lane] = make_float2(mx, mn);
    }
    __shared__ double sred[256];
    sred[threadIdx.x] = ax;
    __syncthreads();
    if (sub == 0)
        px[(size_t)blockIdx.x * 64 + lane] =
            sred[lane] + sred[lane + 64] + sred[lane + 128] + sred[lane + 192];
    __syncthreads();
    sred[threadIdx.x] = ax2;
    __syncthreads();
    if (sub == 0)
        px2[(size_t)blockIdx.x * 64 + lane] =
            sred[lane] + sred[lane + 64] + sred[lane + 128] + sred[lane + 192];
}

extern "C" __global__ __launch_bounds__(256)
void k_finalize(const double* __restrict__ px, const double* __restrict__ px2,
                const uint32_t* __restrict__ ctr,
                const float* __restrict__ gamma, const float* __restrict__ beta,
                float* __restrict__ scale, float* __restrict__ shift)
{
    int c = threadIdx.x & 63;
    int g = threadIdx.x >> 6;
    double sx = 0.0, sx2 = 0.0;
    for (int b = g; b < SBc; b += 4) {
        sx  += px[(size_t)b * 64 + c];
        sx2 += px2[(size_t)b * 64 + c];
    }
    __shared__ double sr[256];
    sr[threadIdx.x] = sx;
    __syncthreads();
    double tsx = 0.0;
    if (g == 0) tsx = sr[c] + sr[c + 64] + sr[c + 128] + sr[c + 192];
    __syncthreads();
    sr[threadIdx.x] = sx2;
    __syncthreads();
    if (g == 0) {
        double tsx2 = sr[c] + sr[c + 64] + sr[c + 128] + sr[c + 192];
        uint32_t nvu = ctr[2];                 // low32 of packed = nvalid
        if (nvu < 1u) nvu = 1u;
        double nv = (double)nvu;
        double mu = tsx / nv;
        double var = tsx2 / nv - mu * mu;
        float r = (float)(1.0 / sqrt(var + 0.001));
        float sc = gamma[c] * r;
        scale[c] = sc;
        shift[c] = fmaf(-(float)mu, sc, beta[c]);
    }
}

// Expand compact -> full canvas: per cell, sel = (s>=0 ? max : min),
// v = relu(s*sel + t); empty pillar -> 0. Fully-coalesced canvas write
// (replaces any canvas memset). 128 segs x 64 ch via LDS tile (pad 65).
extern "C" __global__ __launch_bounds__(256)
void k_expand(const float2* __restrict__ compact, const int* __restrict__ denseOf,
              const float* __restrict__ scale, const float* __restrict__ shift,
              float* __restrict__ out)
{
    __shared__ int sdense[128];
    __shared__ float tile[128 * 65];
    int tid = threadIdx.x;
    int s0 = blockIdx.x * 128;
    if (tid < 128) sdense[tid] = denseOf[s0 + tid];
    __syncthreads();
    int w = tid >> 6, lane = tid & 63;
    float sc = scale[lane], sh = shift[lane];
    for (int k = 0; k < 32; k++) {
        int p = w * 32 + k;
        int d = sdense[p];
        float v = 0.0f;
        if (d >= 0) {
            float2 mm = compact[(size_t)d * 64 + lane];
            float sel = (sc >= 0.0f) ? mm.x : mm.y;
            v = fmaxf(fmaf(sel, sc, sh), 0.0f);
        }
        tile[p * 65 + lane] = v;
    }
    __syncthreads();
    int gx0 = s0 & (GXc - 1);
    int gy  = (s0 >> 9) & (GYc - 1);
    int bt  = s0 >> 18;            // b*T + t
    int t   = bt % Tc;
    int b   = bt / Tc;
    int p   = tid & 127;
    int ch  = tid >> 7;            // 0 or 1
    size_t rowbase = ((size_t)gy << 9) + gx0 + p;
    for (int cc = 0; cc < 64; cc += 2) {
        int c = cc + ch;
        size_t o = ((((size_t)b * Cc + c) * Tc + t) << 18) + rowbase;
        out[o] = tile[p * 65 + c];
    }
}

extern "C" void kernel_launch(void* const* d_in, const int* in_sizes, int n_in,
                              void* d_out, int out_size, void* d_ws, size_t ws_size,
                              hipStream_t stream)
{
    const float* pts   = (const float*)d_in[0];
    const float* W     = (const float*)d_in[1];
    const float* gamma = (const float*)d_in[2];
    const float* beta  = (const float*)d_in[3];
    int n = in_sizes[0] / 6;

    uint8_t* ws = (uint8_t*)d_ws;
    size_t npad = ((size_t)n * 4 + 255) & ~(size_t)255;
    const size_t OFF_CTR    = 0;                                   // 256 B
    const size_t OFF_COUNTS = 256;
    const size_t ZERO_END   = OFF_COUNTS + (size_t)NSEG * 4;       // 10.5 MB
    const size_t OFF_PX     = ZERO_END;
    const size_t OFF_PX2    = OFF_PX  + (size_t)SBc * 64 * 8;
    const size_t OFF_SCALE  = OFF_PX2 + (size_t)SBc * 64 * 8;
    const size_t OFF_SHIFT  = OFF_SCALE + 256;
    const size_t OFF_DENSE  = OFF_SHIFT + 256;
    const size_t OFF_OFFOF  = OFF_DENSE + (size_t)NSEG * 4;
    const size_t OFF_SEGOF  = OFF_OFFOF + (size_t)NSEG * 4;
    const size_t OFF_RANK   = OFF_SEGOF + npad;
    const size_t OFF_SDENSE = OFF_RANK + npad;
    const size_t OFF_LIST   = OFF_SDENSE + npad;
    const size_t OFF_COMP   = OFF_LIST + npad;     // float2 [n][64] worst case

    uint32_t* ctr     = (uint32_t*)(ws + OFF_CTR);
    uint32_t* counts  = (uint32_t*)(ws + OFF_COUNTS);
    double*   px      = (double*)(ws + OFF_PX);
    double*   px2     = (double*)(ws + OFF_PX2);
    float*    scale   = (float*)(ws + OFF_SCALE);
    float*    shift   = (float*)(ws + OFF_SHIFT);
    int*      denseOf = (int*)(ws + OFF_DENSE);
    uint32_t* offOf   = (uint32_t*)(ws + OFF_OFFOF);
    int*      segOf   = (int*)(ws + OFF_SEGOF);
    uint32_t* rankOf  = (uint32_t*)(ws + OFF_RANK);
    int*      segOfD  = (int*)(ws + OFF_SDENSE);
    uint32_t* list    = (uint32_t*)(ws + OFF_LIST);
    float2*   compact = (float2*)(ws + OFF_COMP);

    hipMemsetAsync(ws, 0, ZERO_END, stream);   // ctr + counts only (10.5 MB)

    k_count   <<<(n + 255) / 256, 256, 0, stream>>>(pts, counts, ctr, segOf, rankOf, n);
    k_offsets <<<(NSEG + 1023) / 1024, 1024, 0, stream>>>(counts, ctr, denseOf,
                                                          offOf, segOfD);
    k_fill    <<<(n + 255) / 256, 256, 0, stream>>>(segOf, rankOf, offOf, list, n);
    k_pillar  <<<SBc, 256, 0, stream>>>(pts, counts, offOf, segOfD, list, W, ctr,
                                        compact, px, px2);
    k_finalize<<<1, 256, 0, stream>>>(px, px2, ctr, gamma, beta, scale, shift);
    k_expand  <<<NSEG / 128, 256, 0, stream>>>(compact, denseOf, scale, shift,
                                               (float*)d_out);
}

// Round 8
// 1151.518 us; speedup vs baseline: 2.0878x; 1.0333x over previous
//
#include <hip/hip_runtime.h>
#include <stdint.h>
#include <float.h>

// PillarFeatureNet on MI355X — round 8: single-pass pillar via mean
// factorization;  list carries point payload (float4) to kill the
// dependent gather chain.
// B=2, T=5, GX=GY=512, C=64, N=600000. Output (B,C,T,GY,GX) f32 = 671 MB.
//
// Algebra: xc = pbase(point) - md(pillar,ch), where
//   pbase = x(w0+w4+w7) + y(w1+w5+w8) + z(w2+w6) + it*w3 - (ctr0*w7+ctr1*w8)
//   md    = m0*w4 + m1*w5 + m2*w6           (m = pillar xyz mean)
// max_p xc = max_p pbase - md (exact); BN stats via
//   Sum xc   = Sum pb  - cnt*md
//   Sum xc^2 = Sum pb^2 - 2 md Sum pb + cnt md^2
// Voxelization numerics: (x+51.2f)*5.0f IEEE-pinned f32 — membership-
// critical, matches the oracle's multiply-by-reciprocal. DO NOT TOUCH.

#define GXc 512
#define GYc 512
#define Bc  2
#define Tc  5
#define Cc  64
#define NSEG (Bc * Tc * GYc * GXc)   // 2,621,440
#define SBc 2048                     // stat partial rows (= k_pillar grid)

__device__ __forceinline__ bool point_prep(const float* __restrict__ p,
    float& x, float& y, float& z, float& inten,
    int& bid, int& tid, int& cx, int& cy, int& seg)
{
    float b0 = p[0];
    x = p[1]; y = p[2]; z = p[3]; inten = p[4];
    float tf = p[5];
    float cf0 = __fmul_rn(__fadd_rn(x, 51.2f), 5.0f);
    float cf1 = __fmul_rn(__fadd_rn(y, 51.2f), 5.0f);
    bool valid = (cf0 >= 0.0f) && (cf0 < 512.0f) && (cf1 >= 0.0f) && (cf1 < 512.0f);
    int icx = (int)cf0; icx = icx < 0 ? 0 : (icx > GXc - 1 ? GXc - 1 : icx);
    int icy = (int)cf1; icy = icy < 0 ? 0 : (icy > GYc - 1 ? GYc - 1 : icy);
    cx = icx; cy = icy;
    bid = (int)b0;
    tid = (int)tf;
    seg = ((bid * Tc + tid) * GYc + cy) * GXc + cx;
    return valid;
}

// srArr[i] = {seg, rank} ({0xFFFFFFFF,0} if invalid)
extern "C" __global__ __launch_bounds__(256)
void k_count(const float* __restrict__ pts, uint32_t* __restrict__ counts,
             uint2* __restrict__ srArr, int n)
{
    int i = blockIdx.x * 256 + threadIdx.x;
    if (i >= n) return;
    float x, y, z, it; int bid, tid, cx, cy, seg;
    bool v = point_prep(pts + (size_t)i * 6, x, y, z, it, bid, tid, cx, cy, seg);
    if (!v) { srArr[i] = make_uint2(0xFFFFFFFFu, 0u); return; }
    uint32_t r = atomicAdd(&counts[seg], 1u);
    srArr[i] = make_uint2((uint32_t)seg, r);
}

// Dense-id + offset assignment via block scan; ONE u64 atomic per block.
// ctr[2..3] = packed u64 (low32 = total valid points, high32 = nPillars).
// Also emits per-dense packed {off,cnt} for k_pillar.
extern "C" __global__ __launch_bounds__(1024)
void k_offsets(const uint32_t* __restrict__ counts, uint32_t* __restrict__ ctr,
               int* __restrict__ denseOf, uint32_t* __restrict__ offOf,
               int* __restrict__ segOfDense, uint2* __restrict__ cntoff)
{
    int tid = threadIdx.x;
    int i = blockIdx.x * 1024 + tid;
    uint32_t cnt = (i < NSEG) ? counts[i] : 0u;
    uint32_t occ = (cnt > 0u) ? 1u : 0u;
    unsigned long long v = ((unsigned long long)occ << 32) | (unsigned long long)cnt;
    unsigned long long inc = v;
    int lane = tid & 63, wid = tid >> 6;
    #pragma unroll
    for (int d = 1; d < 64; d <<= 1) {
        unsigned long long t = __shfl_up(inc, d, 64);
        if (lane >= d) inc += t;
    }
    __shared__ unsigned long long wtot[16];
    __shared__ unsigned long long wbase[16];
    __shared__ unsigned long long gbase;
    if (lane == 63) wtot[wid] = inc;
    __syncthreads();
    if (wid == 0) {
        unsigned long long w = (lane < 16) ? wtot[lane] : 0ull;
        unsigned long long s = w;
        #pragma unroll
        for (int d = 1; d < 16; d <<= 1) {
            unsigned long long t = __shfl_up(s, d, 64);
            if (lane >= d) s += t;
        }
        if (lane < 16) wbase[lane] = s - w;
        if (lane == 15)
            gbase = atomicAdd((unsigned long long*)(ctr + 2), s);
    }
    __syncthreads();
    if (i >= NSEG) return;
    unsigned long long ex = gbase + wbase[wid] + (inc - v);
    if (occ) {
        uint32_t d = (uint32_t)(ex >> 32);
        uint32_t o = (uint32_t)ex;
        denseOf[i] = (int)d;
        offOf[i] = o;
        segOfDense[d] = i;
        cntoff[d] = make_uint2(o, cnt);
    } else {
        denseOf[i] = -1;
    }
}

// Deposit point payload (x,y,z,inten) into its pillar's list slot.
extern "C" __global__ __launch_bounds__(256)
void k_fill(const float* __restrict__ pts, const uint2* __restrict__ srArr,
            const uint32_t* __restrict__ offOf, float4* __restrict__ list4, int n)
{
    int i = blockIdx.x * 256 + threadIdx.x;
    if (i >= n) return;
    uint2 sr = srArr[i];
    if (sr.x == 0xFFFFFFFFu) return;
    const float* P = pts + (size_t)i * 6;
    list4[offOf[sr.x] + sr.y] = make_float4(P[1], P[2], P[3], P[4]);
}

// Grid-stride over occupied pillars; one wave per pillar, lane = channel.
// SINGLE pass per pillar: one float4 load per point; pbase reduction;
// (max,min) pre-BN stored; f64 BN-stat partials per block.
extern "C" __global__ __launch_bounds__(256)
void k_pillar(const float4* __restrict__ list4, const uint2* __restrict__ cntoff,
              const int* __restrict__ segOfDense, const float* __restrict__ W,
              const uint32_t* __restrict__ ctr, float2* __restrict__ compact,
              double* __restrict__ px, double* __restrict__ px2)
{
    int lane = threadIdx.x & 63;
    int sub  = threadIdx.x >> 6;
    uint32_t nP = ctr[3];                       // high32 of packed counter
    float w0 = W[0 * Cc + lane], w1 = W[1 * Cc + lane], w2 = W[2 * Cc + lane];
    float w3 = W[3 * Cc + lane], w4 = W[4 * Cc + lane], w5 = W[5 * Cc + lane];
    float w6 = W[6 * Cc + lane], w7 = W[7 * Cc + lane], w8 = W[8 * Cc + lane];
    float wx = w0 + w4 + w7, wy = w1 + w5 + w8, wz = w2 + w6;
    double ax = 0.0, ax2 = 0.0;
    for (uint32_t d = blockIdx.x * 4 + sub; d < nP; d += (uint32_t)gridDim.x * 4) {
        int seg = segOfDense[d];
        uint2 co = cntoff[d];
        uint32_t off = co.x, cnt = co.y;
        int cx = seg & (GXc - 1);
        int cy = (seg >> 9) & (GYc - 1);
        float ctr0 = __fadd_rn(__fadd_rn(__fmul_rn((float)cx, 0.2f), 0.1f), -51.2f);
        float ctr1 = __fadd_rn(__fadd_rn(__fmul_rn((float)cy, 0.2f), 0.1f), -51.2f);
        float cconst = -(ctr0 * w7 + ctr1 * w8);
        float sx = 0.f, sy = 0.f, sz = 0.f;
        float mx = -FLT_MAX, mn = FLT_MAX;
        double spb = 0.0, spb2 = 0.0;
        for (uint32_t p = 0; p < cnt; p++) {
            float4 P = list4[off + p];
            sx += P.x; sy += P.y; sz += P.z;
            float pb = fmaf(P.x, wx,
                       fmaf(P.y, wy,
                       fmaf(P.z, wz,
                       fmaf(P.w, w3, cconst))));
            mx = fmaxf(mx, pb);
            mn = fminf(mn, pb);
            spb += (double)pb;
            spb2 = fma((double)pb, (double)pb, spb2);
        }
        float fc = (float)cnt;
        float m0 = sx / fc, m1 = sy / fc, m2 = sz / fc;
        float md = fmaf(m0, w4, fmaf(m1, w5, m2 * w6));
        compact[(size_t)d * 64 + lane] = make_float2(mx - md, mn - md);
        double mdd = (double)md, cd = (double)cnt;
        ax  += spb - cd * mdd;
        ax2 += spb2 - 2.0 * mdd * spb + cd * mdd * mdd;
    }
    __shared__ double sred[256];
    sred[threadIdx.x] = ax;
    __syncthreads();
    if (sub == 0)
        px[(size_t)blockIdx.x * 64 + lane] =
            sred[lane] + sred[lane + 64] + sred[lane + 128] + sred[lane + 192];
    __syncthreads();
    sred[threadIdx.x] = ax2;
    __syncthreads();
    if (sub == 0)
        px2[(size_t)blockIdx.x * 64 + lane] =
            sred[lane] + sred[lane + 64] + sred[lane + 128] + sred[lane + 192];
}

extern "C" __global__ __launch_bounds__(256)
void k_finalize(const double* __restrict__ px, const double* __restrict__ px2,
                const uint32_t* __restrict__ ctr,
                const float* __restrict__ gamma, const float* __restrict__ beta,
                float* __restrict__ scale, float* __restrict__ shift)
{
    int c = threadIdx.x & 63;
    int g = threadIdx.x >> 6;
    double sx = 0.0, sx2 = 0.0;
    for (int b = g; b < SBc; b += 4) {
        sx  += px[(size_t)b * 64 + c];
        sx2 += px2[(size_t)b * 64 + c];
    }
    __shared__ double sr[256];
    sr[threadIdx.x] = sx;
    __syncthreads();
    double tsx = 0.0;
    if (g == 0) tsx = sr[c] + sr[c + 64] + sr[c + 128] + sr[c + 192];
    __syncthreads();
    sr[threadIdx.x] = sx2;
    __syncthreads();
    if (g == 0) {
        double tsx2 = sr[c] + sr[c + 64] + sr[c + 128] + sr[c + 192];
        uint32_t nvu = ctr[2];                 // low32 of packed = nvalid
        if (nvu < 1u) nvu = 1u;
        double nv = (double)nvu;
        double mu = tsx / nv;
        double var = tsx2 / nv - mu * mu;
        float r = (float)(1.0 / sqrt(var + 0.001));
        float sc = gamma[c] * r;
        scale[c] = sc;
        shift[c] = fmaf(-(float)mu, sc, beta[c]);
    }
}

// Expand compact -> full canvas: sel = (s>=0 ? max : min), v = relu(s*sel+t);
// empty pillar -> 0. Fully-coalesced canvas write (replaces canvas memset).
extern "C" __global__ __launch_bounds__(256)
void k_expand(const float2* __restrict__ compact, const int* __restrict__ denseOf,
              const float* __restrict__ scale, const float* __restrict__ shift,
              float* __restrict__ out)
{
    __shared__ int sdense[128];
    __shared__ float tile[128 * 65];
    int tid = threadIdx.x;
    int s0 = blockIdx.x * 128;
    if (tid < 128) sdense[tid] = denseOf[s0 + tid];
    __syncthreads();
    int w = tid >> 6, lane = tid & 63;
    float sc = scale[lane], sh = shift[lane];
    for (int k = 0; k < 32; k++) {
        int p = w * 32 + k;
        int d = sdense[p];
        float v = 0.0f;
        if (d >= 0) {
            float2 mm = compact[(size_t)d * 64 + lane];
            float sel = (sc >= 0.0f) ? mm.x : mm.y;
            v = fmaxf(fmaf(sel, sc, sh), 0.0f);
        }
        tile[p * 65 + lane] = v;
    }
    __syncthreads();
    int gx0 = s0 & (GXc - 1);
    int gy  = (s0 >> 9) & (GYc - 1);
    int bt  = s0 >> 18;            // b*T + t
    int t   = bt % Tc;
    int b   = bt / Tc;
    int p   = tid & 127;
    int ch  = tid >> 7;            // 0 or 1
    size_t rowbase = ((size_t)gy << 9) + gx0 + p;
    for (int cc = 0; cc < 64; cc += 2) {
        int c = cc + ch;
        size_t o = ((((size_t)b * Cc + c) * Tc + t) << 18) + rowbase;
        out[o] = tile[p * 65 + c];
    }
}

extern "C" void kernel_launch(void* const* d_in, const int* in_sizes, int n_in,
                              void* d_out, int out_size, void* d_ws, size_t ws_size,
                              hipStream_t stream)
{
    const float* pts   = (const float*)d_in[0];
    const float* W     = (const float*)d_in[1];
    const float* gamma = (const float*)d_in[2];
    const float* beta  = (const float*)d_in[3];
    int n = in_sizes[0] / 6;

    uint8_t* ws = (uint8_t*)d_ws;
    size_t npad = ((size_t)n * 4 + 255) & ~(size_t)255;
    const size_t OFF_CTR    = 0;                                   // 256 B
    const size_t OFF_COUNTS = 256;
    const size_t ZERO_END   = OFF_COUNTS + (size_t)NSEG * 4;       // 10.5 MB
    const size_t OFF_PX     = ZERO_END;
    const size_t OFF_PX2    = OFF_PX  + (size_t)SBc * 64 * 8;
    const size_t OFF_SCALE  = OFF_PX2 + (size_t)SBc * 64 * 8;
    const size_t OFF_SHIFT  = OFF_SCALE + 256;
    const size_t OFF_DENSE  = OFF_SHIFT + 256;
    const size_t OFF_OFFOF  = OFF_DENSE + (size_t)NSEG * 4;
    const size_t OFF_SDENSE = OFF_OFFOF + (size_t)NSEG * 4;
    const size_t OFF_CNTOFF = OFF_SDENSE + (size_t)NSEG * 4;       // uint2[NSEG]
    const size_t OFF_SR     = OFF_CNTOFF + (size_t)NSEG * 8;       // uint2[n]
    const size_t OFF_LIST   = OFF_SR + npad * 2;                   // float4[n]
    const size_t OFF_COMP   = OFF_LIST + npad * 4;                 // float2[nP][64]

    uint32_t* ctr     = (uint32_t*)(ws + OFF_CTR);
    uint32_t* counts  = (uint32_t*)(ws + OFF_COUNTS);
    double*   px      = (double*)(ws + OFF_PX);
    double*   px2     = (double*)(ws + OFF_PX2);
    float*    scale   = (float*)(ws + OFF_SCALE);
    float*    shift   = (float*)(ws + OFF_SHIFT);
    int*      denseOf = (int*)(ws + OFF_DENSE);
    uint32_t* offOf   = (uint32_t*)(ws + OFF_OFFOF);
    int*      segOfD  = (int*)(ws + OFF_SDENSE);
    uint2*    cntoff  = (uint2*)(ws + OFF_CNTOFF);
    uint2*    srArr   = (uint2*)(ws + OFF_SR);
    float4*   list4   = (float4*)(ws + OFF_LIST);
    float2*   compact = (float2*)(ws + OFF_COMP);

    hipMemsetAsync(ws, 0, ZERO_END, stream);   // ctr + counts only (10.5 MB)

    k_count   <<<(n + 255) / 256, 256, 0, stream>>>(pts, counts, srArr, n);
    k_offsets <<<(NSEG + 1023) / 1024, 1024, 0, stream>>>(counts, ctr, denseOf,
                                                          offOf, segOfD, cntoff);
    k_fill    <<<(n + 255) / 256, 256, 0, stream>>>(pts, srArr, offOf, list4, n);
    k_pillar  <<<SBc, 256, 0, stream>>>(list4, cntoff, segOfD, W, ctr,
                                        compact, px, px2);
    k_finalize<<<1, 256, 0, stream>>>(px, px2, ctr, gamma, beta, scale, shift);
    k_expand  <<<NSEG / 128, 256, 0, stream>>>(compact, denseOf, scale, shift,
                                               (float*)d_out);
}